// Round 7
// baseline (337.927 us; speedup 1.0000x reference)
//
#include <hip/hip_runtime.h>
#include <math.h>

// PositionFeaturizer on MI355X — round 14 (DIAGNOSTIC):
//  * gemm23 REVERTED (85.7 us measured vs 66 for gemm2+gemm3+gap in r12).
//    Back to r12 structure: gemm256<4> + edge + gemm256<1> + gemm_nt<2,2>.
//  * REP=3 template repeat (stage+K-loop+drain x3, identical numerics,
//    epilogue once) on prep_wln / gemm256<4> / gemm256<1> / gemm_nt<2,2>:
//    makes any kernel with true dur >= ~14 us visible above the 40-us
//    harness-fill line WITH its real counters. dur_us inflates by design.
//  * Predictions: gemm256s true ~35-45 us each (visible at ~100-140 at
//    REP3); conflict counter discriminates broken-swizzle vs latency.

typedef unsigned short u16;
typedef __attribute__((ext_vector_type(8))) short bf16x8;   // 8 bf16 in 4 VGPRs
typedef __attribute__((ext_vector_type(4))) float f32x4;
typedef __attribute__((ext_vector_type(2))) float f32x2;

constexpr int N_NODES = 16384;
constexpr int E_EDGES = 262144;
constexpr int D = 512;
constexpr int KIN = 576;    // 536 padded to 9*64

// workspace layout (bytes)
constexpr size_t OFF_ZATT = 0;                       // 16384*512*2  = 16,777,216
constexpr size_t OFF_ZCAT = 16777216;                // 16384*576*2  = 18,874,368
constexpr size_t OFF_WQK  = 35651584;                // 1024*512*2   = 1,048,576
constexpr size_t OFF_BQK  = 36700160;                // 1024*4       = 4,096
constexpr size_t OFF_WIN  = 36704256;                // 1024*576*2   = 1,179,648
constexpr size_t OFF_WOUT = 37883904;                // 512*1024*2   = 1,048,576
constexpr size_t OFF_QK   = 38932480;                // 16384*1024*1 = 16,777,216 (fp8)
constexpr size_t OFF_BKT  = 55775232;                // 16384*64*4 = 4,194,304
constexpr size_t OFF_HBF  = 59969536;                // 16384*1024*2 = 33,554,432
constexpr size_t OFF_REC  = 93523968;                // 262144*64 = 16,777,216
constexpr size_t OFF_CNTP = 110301184;               // 16384*64 = 1,048,576

static __device__ __forceinline__ u16 f2bf(float f) {
  union { float f; unsigned int u; } v; v.f = f;
  unsigned int u = v.u;
  u = u + 0x7FFFu + ((u >> 16) & 1u);   // RNE
  return (u16)(u >> 16);
}
// async global->LDS, 16 B per lane; LDS dest = wave-uniform base + lane*16
static __device__ __forceinline__ void gload16(const u16* g, u16* l) {
  __builtin_amdgcn_global_load_lds(
      (const __attribute__((address_space(1))) unsigned int*)g,
      (__attribute__((address_space(3))) unsigned int*)l, 16, 0, 0);
}

// ---------------------------------------------------------------- CSR + edge records (1024 blocks)
__global__ __launch_bounds__(256) void prep_edges(
    const int* __restrict__ row_index,
    const float* __restrict__ att_bias, const float* __restrict__ dist,
    const float* __restrict__ src_pos, const int* __restrict__ src_index,
    const int* __restrict__ org_to_src,
    int* __restrict__ cntp, int* __restrict__ bucket, float* __restrict__ rec)
{
  const int gid = blockIdx.x * 256 + threadIdx.x;   // < E_EDGES
  const int r = row_index[gid];
  const int s = src_index[gid];
  const float dv = dist[gid];
  float4 q0, q1, q2, q3;
  q0.x = att_bias[gid];
  q0.y = att_bias[(size_t)1 * E_EDGES + gid];
  q0.z = att_bias[(size_t)2 * E_EDGES + gid];
  q0.w = att_bias[(size_t)3 * E_EDGES + gid];
  q1.x = att_bias[(size_t)4 * E_EDGES + gid];
  q1.y = att_bias[(size_t)5 * E_EDGES + gid];
  q1.z = att_bias[(size_t)6 * E_EDGES + gid];
  q1.w = att_bias[(size_t)7 * E_EDGES + gid];
  q2.x = (dv == 0.f) ? 0.f : 1.f / dv;   // matches ref: inv = 1/dist, then mul
  q2.y = src_pos[(size_t)s * 3 + 0];
  q2.z = src_pos[(size_t)s * 3 + 1];
  q2.w = src_pos[(size_t)s * 3 + 2];
  q3.x = __int_as_float(org_to_src[s]);
  q3.y = 0.f; q3.z = 0.f; q3.w = 0.f;
  float4* rg = (float4*)(rec + (size_t)gid * 16);
  rg[0] = q0; rg[1] = q1; rg[2] = q2; rg[3] = q3;
  const int p = atomicAdd(&cntp[r * 16], 1);   // 1 counter per 64-B line
  if (p < 64) bucket[(size_t)r * 64 + p] = gid;
}

// ---------------------------------------------------------------- weights cast + dual LN (REP: diagnostic repeat)
template <int REP>
__global__ __launch_bounds__(256) void prep_wln(
    const float* __restrict__ Wq, const float* __restrict__ Wk,
    const float* __restrict__ bq, const float* __restrict__ bk,
    const float* __restrict__ W_in, const float* __restrict__ W_out,
    u16* __restrict__ wqk, float* __restrict__ bqk,
    u16* __restrict__ win, u16* __restrict__ wout,
    const float* __restrict__ x,
    const float* __restrict__ g1, const float* __restrict__ b1,
    const float* __restrict__ g2, const float* __restrict__ b2,
    u16* __restrict__ zatt, u16* __restrict__ zcat)
{
  for (int rep = 0; rep < REP; ++rep) {
    if (blockIdx.x < 2304) {
      const int gid = blockIdx.x * 256 + threadIdx.x;
      if (gid < 512 * 1024) {
        wqk[gid]  = f2bf(gid < 512 * 512 ? Wq[gid] : Wk[gid - 512 * 512]);
        wout[gid] = f2bf(W_out[gid]);
      }
      if (gid < 1024 * KIN) {
        const int r = gid / KIN, c = gid - r * KIN;
        win[gid] = f2bf(c < 536 ? W_in[r * 536 + c] : 0.f);
      }
      if (gid < 1024) bqk[gid] = gid < 512 ? bq[gid] : bk[gid - 512];
    } else {
      // dual layernorm, wave-per-row (4096 blocks x 4 rows)
      const int row = (blockIdx.x - 2304) * 4 + (threadIdx.x >> 6);
      const int l = threadIdx.x & 63;
      const float* xr = x + (size_t)row * D + l * 8;
      const float4 v0 = *(const float4*)(xr);
      const float4 v1 = *(const float4*)(xr + 4);
      float s  = v0.x + v0.y + v0.z + v0.w + v1.x + v1.y + v1.z + v1.w;
      float s2 = v0.x * v0.x + v0.y * v0.y + v0.z * v0.z + v0.w * v0.w
               + v1.x * v1.x + v1.y * v1.y + v1.z * v1.z + v1.w * v1.w;
#pragma unroll
      for (int m = 1; m < 64; m <<= 1) {
        s  += __shfl_xor(s, m, 64);
        s2 += __shfl_xor(s2, m, 64);
      }
      const float mu = s * (1.f / D);
      const float var = s2 * (1.f / D) - mu * mu;
      const float rs = rsqrtf(var + 1e-5f);
      const int c0 = l * 8;
      const float4 ga0 = *(const float4*)(g1 + c0), ga1 = *(const float4*)(g1 + c0 + 4);
      const float4 ba0 = *(const float4*)(b1 + c0), ba1 = *(const float4*)(b1 + c0 + 4);
      const float4 gm0 = *(const float4*)(g2 + c0), gm1 = *(const float4*)(g2 + c0 + 4);
      const float4 bm0 = *(const float4*)(b2 + c0), bm1 = *(const float4*)(b2 + c0 + 4);
      float n[8] = { (v0.x - mu) * rs, (v0.y - mu) * rs, (v0.z - mu) * rs, (v0.w - mu) * rs,
                     (v1.x - mu) * rs, (v1.y - mu) * rs, (v1.z - mu) * rs, (v1.w - mu) * rs };
      const float ga[8] = { ga0.x, ga0.y, ga0.z, ga0.w, ga1.x, ga1.y, ga1.z, ga1.w };
      const float ba[8] = { ba0.x, ba0.y, ba0.z, ba0.w, ba1.x, ba1.y, ba1.z, ba1.w };
      const float gm[8] = { gm0.x, gm0.y, gm0.z, gm0.w, gm1.x, gm1.y, gm1.z, gm1.w };
      const float bm[8] = { bm0.x, bm0.y, bm0.z, bm0.w, bm1.x, bm1.y, bm1.z, bm1.w };
      bf16x8 za, zc;
#pragma unroll
      for (int i = 0; i < 8; ++i) {
        za[i] = (short)f2bf(n[i] * ga[i] + ba[i]);
        zc[i] = (short)f2bf(n[i] * gm[i] + bm[i]);
      }
      *(bf16x8*)(zatt + (size_t)row * D + c0) = za;
      *(bf16x8*)(zcat + (size_t)row * KIN + c0) = zc;
      if (l < 32) ((unsigned int*)(zcat + (size_t)row * KIN + D))[l] = 0;
    }
  }
}

// ---------------------------------------------------------------- 256^2 8-wave deep-pipelined NT GEMM
#define MM_BLK(AF, BF, NB) do {                                               \
  __builtin_amdgcn_s_setprio(1);                                              \
  _Pragma("unroll")                                                           \
  for (int mi = 0; mi < 8; ++mi) {                                            \
    acc[mi][NB]     = __builtin_amdgcn_mfma_f32_16x16x32_bf16(AF[mi], BF[0], acc[mi][NB], 0, 0, 0);     \
    acc[mi][NB + 1] = __builtin_amdgcn_mfma_f32_16x16x32_bf16(AF[mi], BF[1], acc[mi][NB + 1], 0, 0, 0); \
  }                                                                           \
  __builtin_amdgcn_s_setprio(0);                                              \
} while (0)

template <int EPI, int REP>
__global__ __launch_bounds__(512, 2) void gemm256(
    const u16* __restrict__ A, const u16* __restrict__ B,
    const float* __restrict__ bias,
    void* __restrict__ Cout, int M, int Nn, int K)
{
  extern __shared__ __align__(16) u16 lds[];   // 65536 u16 = 128 KiB
  const int tid = threadIdx.x;
  const int lane = tid & 63;
  const int wave = tid >> 6;          // 0..7
  const int wave_m = wave >> 2;
  const int wave_n = wave & 3;
  const int m0 = blockIdx.x * 256;
  const int n0 = blockIdx.y * 256;
  const int fr = lane & 15;
  const int fq = lane >> 4;
  const int NT = K >> 6;
  const int sw = (fq ^ ((fr >> 1) & 3)) * 8;

  f32x4 acc[8][4];

  auto stageA = [&](int slot, int ktile, int kh) {
    u16* base = lds + slot * 8192;
    const int kb = ktile * 64 + kh * 32;
#pragma unroll
    for (int r = 0; r < 2; ++r) {
      const int g = r * 512 + tid;
      const int row = g >> 2;
      const int gs = (g & 3) ^ ((row >> 1) & 3);
      gload16(A + (size_t)(m0 + row) * K + kb + gs * 8,
              base + (r * 512 + wave * 64) * 8);
    }
  };
  auto stageB = [&](int slot, int ktile, int kh) {
    u16* base = lds + 32768 + slot * 8192;
    const int kb = ktile * 64 + kh * 32;
#pragma unroll
    for (int r = 0; r < 2; ++r) {
      const int g = r * 512 + tid;
      const int row = g >> 2;
      const int gs = (g & 3) ^ ((row >> 1) & 3);
      gload16(B + (size_t)(n0 + row) * K + kb + gs * 8,
              base + (r * 512 + wave * 64) * 8);
    }
  };
  auto ldA = [&](bf16x8 (&af)[8], int slot) {
    const u16* p = lds + slot * 8192 + (wave_m * 128 + fr) * 32 + sw;
#pragma unroll
    for (int mi = 0; mi < 8; ++mi)
      af[mi] = *(const bf16x8*)(p + mi * 16 * 32);
  };
  auto ldB = [&](bf16x8 (&bf)[2], int slot, int nh) {
    const u16* p = lds + 32768 + slot * 8192 + (wave_n * 64 + nh * 32 + fr) * 32 + sw;
    bf[0] = *(const bf16x8*)(p);
    bf[1] = *(const bf16x8*)(p + 16 * 32);
  };

  for (int rep = 0; rep < REP; ++rep) {
#pragma unroll
    for (int i = 0; i < 8; ++i)
#pragma unroll
      for (int j = 0; j < 4; ++j) acc[i][j] = 0.f;

    stageA(0, 0, 0); stageB(0, 0, 0);
    stageA(1, 0, 1); stageB(1, 0, 1);
    stageA(2, 1, 0); stageB(2, 1, 0);
    stageA(3, 1, 1);
    asm volatile("s_waitcnt vmcnt(10)" ::: "memory");
    __builtin_amdgcn_s_barrier();
    asm volatile("" ::: "memory");

    bf16x8 af[8], bf0[2], bf1[2];
    for (int t = 0; t < NT; ++t) {
      const int sa0 = (2 * t) & 3,  sa1 = (2 * t + 1) & 3;
      const int sb1n = (2 * t + 3) & 3;
      const int t1 = (t + 1 >= NT) ? t + 1 - NT : t + 1;
      const int t2 = (t + 2 >= NT) ? t + 2 - NT : t + 2;

      ldA(af, sa0); ldB(bf0, sa0, 0);
      stageB(sb1n, t1, 1);
      __builtin_amdgcn_s_barrier();
      asm volatile("" ::: "memory");
      MM_BLK(af, bf0, 0);
      __builtin_amdgcn_s_barrier();
      asm volatile("" ::: "memory");
      ldB(bf1, sa0, 1);
      stageA(sa0, t2, 0);
      __builtin_amdgcn_s_barrier();
      asm volatile("" ::: "memory");
      MM_BLK(af, bf1, 2);
      asm volatile("s_waitcnt vmcnt(10)" ::: "memory");
      __builtin_amdgcn_s_barrier();
      asm volatile("" ::: "memory");
      ldA(af, sa1); ldB(bf0, sa1, 0);
      stageB(sa0, t2, 0);
      __builtin_amdgcn_s_barrier();
      asm volatile("" ::: "memory");
      MM_BLK(af, bf0, 0);
      __builtin_amdgcn_s_barrier();
      asm volatile("" ::: "memory");
      ldB(bf1, sa1, 1);
      stageA(sa1, t2, 1);
      __builtin_amdgcn_s_barrier();
      asm volatile("" ::: "memory");
      MM_BLK(af, bf1, 2);
      asm volatile("s_waitcnt vmcnt(10)" ::: "memory");
      __builtin_amdgcn_s_barrier();
      asm volatile("" ::: "memory");
    }
    asm volatile("s_waitcnt vmcnt(0)" ::: "memory");
    __builtin_amdgcn_s_barrier();          // rep boundary: all drains visible
    asm volatile("" ::: "memory");
  }

#pragma unroll
  for (int mi = 0; mi < 8; ++mi) {
#pragma unroll
    for (int nj = 0; nj < 4; ++nj) {
      const int col = n0 + wave_n * 64 + nj * 16 + fr;
      const float bv = bias[col];
#pragma unroll
      for (int rr = 0; rr < 4; ++rr) {
        const int row = m0 + wave_m * 128 + mi * 16 + fq * 4 + rr;
        float v = acc[mi][nj][rr] + bv;
        if (EPI == 1) {
          const float nu = -1.5957691216057308f * (v + 0.044715f * v * v * v);
          const float sg = __builtin_amdgcn_rcpf(1.f + __expf(nu));
          ((u16*)Cout)[(size_t)row * Nn + col] = f2bf(v * sg);
        } else {
          const int pk = __builtin_amdgcn_cvt_pk_fp8_f32(v, v, 0, false);
          ((unsigned char*)Cout)[(size_t)row * Nn + col] = (unsigned char)(pk & 0xFF);
        }
      }
    }
  }
}

// ---------------------------------------------------------------- 128^2 NT GEMM (gemm3), granule swizzle
template <int EPI, int WPE, int REP>
__global__ __launch_bounds__(256, WPE) void gemm_nt(
    const u16* __restrict__ A, const u16* __restrict__ B,
    const float* __restrict__ bias, const float* __restrict__ resid,
    void* __restrict__ Cout, int M, int Nn, int K)
{
  constexpr int BM = 128, BN = 128, BK = 32;
  __shared__ __align__(16) u16 As[2 * BM * BK];
  __shared__ __align__(16) u16 Bs[2 * BN * BK];
  const int tid = threadIdx.x;
  const int lane = tid & 63;
  const int wave = tid >> 6;
  const int m0 = blockIdx.x * BM;
  const int n0 = blockIdx.y * BN;
  const int wm = (wave >> 1) * 64;
  const int wn = (wave & 1) * 64;
  const int fr = lane & 15;
  const int fq = lane >> 4;
  const int srow = lane >> 2;
  const int skoff = ((lane & 3) ^ ((srow >> 1) & 3)) * 8;
  const int sw = (fq ^ ((fr >> 1) & 3)) * 8;

  f32x4 acc[4][4];
  for (int rep = 0; rep < REP; ++rep) {
#pragma unroll
    for (int i = 0; i < 4; ++i)
#pragma unroll
      for (int j = 0; j < 4; ++j) acc[i][j] = 0.f;

    for (int k0 = 0; k0 < K; k0 += 2 * BK) {
      __syncthreads();
#pragma unroll
      for (int t = 0; t < 2; ++t) {
#pragma unroll
        for (int r = 0; r < 2; ++r) {
          const int rowbase = r * 64 + wave * 16;
          gload16(A + (size_t)(m0 + rowbase + srow) * K + k0 + t * BK + skoff,
                  As + t * (BM * BK) + rowbase * BK);
          gload16(B + (size_t)(n0 + rowbase + srow) * K + k0 + t * BK + skoff,
                  Bs + t * (BM * BK) + rowbase * BK);
        }
      }
      __syncthreads();
#pragma unroll
      for (int t = 0; t < 2; ++t) {
        bf16x8 af[4], bfr[4];
#pragma unroll
        for (int mi = 0; mi < 4; ++mi)
          af[mi] = *(const bf16x8*)(As + t * (BM * BK) + (wm + mi * 16 + fr) * BK + sw);
#pragma unroll
        for (int ni = 0; ni < 4; ++ni)
          bfr[ni] = *(const bf16x8*)(Bs + t * (BM * BK) + (wn + ni * 16 + fr) * BK + sw);
#pragma unroll
        for (int mi = 0; mi < 4; ++mi)
#pragma unroll
          for (int ni = 0; ni < 4; ++ni)
            acc[mi][ni] = __builtin_amdgcn_mfma_f32_16x16x32_bf16(af[mi], bfr[ni], acc[mi][ni], 0, 0, 0);
      }
    }
    __syncthreads();    // rep boundary
  }

#pragma unroll
  for (int mi = 0; mi < 4; ++mi) {
#pragma unroll
    for (int ni = 0; ni < 4; ++ni) {
      const int col = n0 + wn + ni * 16 + fr;
      const float bv = bias[col];
#pragma unroll
      for (int rr = 0; rr < 4; ++rr) {
        const int row = m0 + wm + mi * 16 + fq * 4 + rr;
        float v = acc[mi][ni][rr] + bv;
        if (EPI == 1) {
          const float nu = -1.5957691216057308f * (v + 0.044715f * v * v * v);
          const float sg = __builtin_amdgcn_rcpf(1.f + __expf(nu));
          ((u16*)Cout)[(size_t)row * Nn + col] = f2bf(v * sg);
        } else if (EPI == 2) {
          ((float*)Cout)[(size_t)row * Nn + col] = v + resid[(size_t)row * Nn + col];
        } else {
          const int pk = __builtin_amdgcn_cvt_pk_fp8_f32(v, v, 0, false);
          ((unsigned char*)Cout)[(size_t)row * Nn + col] = (unsigned char)(pk & 0xFF);
        }
      }
    }
  }
}

// ---------------------------------------------------------------- edge pass (bucket CSR + edge records)
__global__ __launch_bounds__(256) void edge_csr(
    const unsigned char* __restrict__ qk8, const float* __restrict__ rec,
    const int* __restrict__ cntp, const int* __restrict__ bucket,
    const float* __restrict__ pos, u16* __restrict__ zcat)
{
  const int lane = threadIdx.x & 63;
  const int wave = threadIdx.x >> 6;
  const int row = blockIdx.x * 4 + wave;
  const int half = lane >> 5;
  const int sub = lane & 31;
  const int h = sub >> 2, j = sub & 3;
  const int deg = min(cntp[row * 16], 64);
  const int base = row * 64;

  const uint4 qv = *(const uint4*)(qk8 + (size_t)row * 1024 + sub * 16);
  float qf[16];
  {
    const unsigned int* qu = (const unsigned int*)&qv;
#pragma unroll
    for (int i = 0; i < 4; ++i) {
      const f32x2 lo = __builtin_amdgcn_cvt_pk_f32_fp8(qu[i], false);
      const f32x2 hi = __builtin_amdgcn_cvt_pk_f32_fp8(qu[i], true);
      qf[i * 4 + 0] = lo.x; qf[i * 4 + 1] = lo.y;
      qf[i * 4 + 2] = hi.x; qf[i * 4 + 3] = hi.y;
    }
  }

  float accA = 0.f, accB = 0.f;
  const int npair = (deg + 1) >> 1;

  bool ok0 = half < deg;
  int e0 = ok0 ? bucket[base + half] : 0;
  const float* r0 = rec + (size_t)e0 * 16;
  float bias0 = r0[h], invd0 = r0[8];
  float spA0 = (j >= 2) ? r0[7 + j] : 0.f;
  float spB0 = (j == 1) ? r0[11] : 0.f;
  uint4 kv0 = *(const uint4*)(qk8 + (size_t)__float_as_int(r0[12]) * 1024 + 512 + sub * 16);

  bool ok1 = 2 + half < deg;
  int e1 = ok1 ? bucket[base + 2 + half] : 0;
  const float* r1 = rec + (size_t)e1 * 16;
  float bias1 = r1[h], invd1 = r1[8];
  float spA1 = (j >= 2) ? r1[7 + j] : 0.f;
  float spB1 = (j == 1) ? r1[11] : 0.f;
  uint4 kv1 = *(const uint4*)(qk8 + (size_t)__float_as_int(r1[12]) * 1024 + 512 + sub * 16);

  bool ok2 = 4 + half < deg;
  int e2 = ok2 ? bucket[base + 4 + half] : 0;
  const float* r2p = rec + (size_t)e2 * 16;
  float bias2 = r2p[h], invd2 = r2p[8];
  float spA2 = (j >= 2) ? r2p[7 + j] : 0.f;
  float spB2 = (j == 1) ? r2p[11] : 0.f;
  int kr2 = __float_as_int(r2p[12]);

  bool ok3 = 6 + half < deg;
  int e3 = ok3 ? bucket[base + 6 + half] : 0;

  for (int i = 0; i < npair; ++i) {
    const uint4 kv2 = *(const uint4*)(qk8 + (size_t)kr2 * 1024 + 512 + sub * 16);
    const float* r3 = rec + (size_t)e3 * 16;
    const float bias3 = r3[h], invd3 = r3[8];
    const float spA3 = (j >= 2) ? r3[7 + j] : 0.f;
    const float spB3 = (j == 1) ? r3[11] : 0.f;
    const int kr3 = __float_as_int(r3[12]);
    const bool ok4 = 2 * (i + 4) + half < deg;
    const int e4 = ok4 ? bucket[base + 2 * (i + 4) + half] : 0;

    float p;
    {
      const unsigned int* ku = (const unsigned int*)&kv0;
      const f32x2 a0 = __builtin_amdgcn_cvt_pk_f32_fp8(ku[0], false);
      const f32x2 a1 = __builtin_amdgcn_cvt_pk_f32_fp8(ku[0], true);
      const f32x2 b0 = __builtin_amdgcn_cvt_pk_f32_fp8(ku[1], false);
      const f32x2 b1 = __builtin_amdgcn_cvt_pk_f32_fp8(ku[1], true);
      const f32x2 c0 = __builtin_amdgcn_cvt_pk_f32_fp8(ku[2], false);
      const f32x2 c1 = __builtin_amdgcn_cvt_pk_f32_fp8(ku[2], true);
      const f32x2 d0 = __builtin_amdgcn_cvt_pk_f32_fp8(ku[3], false);
      const f32x2 d1 = __builtin_amdgcn_cvt_pk_f32_fp8(ku[3], true);
      p = qf[0] * a0.x;
      p = fmaf(qf[1],  a0.y, p);  p = fmaf(qf[2],  a1.x, p);  p = fmaf(qf[3],  a1.y, p);
      p = fmaf(qf[4],  b0.x, p);  p = fmaf(qf[5],  b0.y, p);  p = fmaf(qf[6],  b1.x, p);
      p = fmaf(qf[7],  b1.y, p);  p = fmaf(qf[8],  c0.x, p);  p = fmaf(qf[9],  c0.y, p);
      p = fmaf(qf[10], c1.x, p);  p = fmaf(qf[11], c1.y, p);  p = fmaf(qf[12], d0.x, p);
      p = fmaf(qf[13], d0.y, p);  p = fmaf(qf[14], d1.x, p);  p = fmaf(qf[15], d1.y, p);
    }
    p += __shfl_xor(p, 1, 64);
    p += __shfl_xor(p, 2, 64);
    float pe = __expf(p * 0.125f + bias0);
    pe = ok0 ? pe : 0.f;
    const float w = pe * invd0;
    accA += (j == 0) ? pe : (j == 1) ? w : w * spA0;
    accB += w * spB0;

    ok0 = ok1; bias0 = bias1; invd0 = invd1; spA0 = spA1; spB0 = spB1; kv0 = kv1;
    ok1 = ok2; bias1 = bias2; invd1 = invd2; spA1 = spA2; spB1 = spB2; kv1 = kv2;
    ok2 = ok3; bias2 = bias3; invd2 = invd3; spA2 = spA3; spB2 = spB3; kr2 = kr3;
    ok3 = ok4; e3 = e4;
  }

  accA += __shfl_xor(accA, 32, 64);
  accB += __shfl_xor(accB, 32, 64);
  const int hb = h << 2;
  const float den  = __shfl(accA, hb + 0, 64);
  const float wsum = __shfl(accA, hb + 1, 64);
  const float wsp01 = __shfl(accA, hb + 2 + (j & 1), 64);
  const float wsp2  = __shfl(accB, hb + 1, 64);
  const float invd = (den != 0.f) ? 1.f / den : 0.f;
  const float rsum = wsum * invd;
  if (half == 0 && j < 3) {
    const float wspj = (j < 2) ? wsp01 : wsp2;
    zcat[(size_t)row * KIN + D + h * 3 + j] = f2bf(wspj * invd - rsum * pos[row * 3 + j]);
  }
}

// ---------------------------------------------------------------- launch
extern "C" void kernel_launch(void* const* d_in, const int* in_sizes, int n_in,
                              void* d_out, int out_size, void* d_ws, size_t ws_size,
                              hipStream_t stream)
{
  const float* x        = (const float*)d_in[0];
  const float* Wq       = (const float*)d_in[1];
  const float* bq       = (const float*)d_in[2];
  const float* Wk       = (const float*)d_in[3];
  const float* bk       = (const float*)d_in[4];
  const float* g_att    = (const float*)d_in[5];
  const float* b_att    = (const float*)d_in[6];
  const float* g_mlp    = (const float*)d_in[7];
  const float* b_mlp    = (const float*)d_in[8];
  const float* W_in     = (const float*)d_in[9];
  const float* b_in     = (const float*)d_in[10];
  const float* W_out    = (const float*)d_in[11];
  const float* b_out    = (const float*)d_in[12];
  const float* att_bias = (const float*)d_in[13];
  const float* dist     = (const float*)d_in[14];
  const float* pos      = (const float*)d_in[15];
  const float* src_pos  = (const float*)d_in[16];
  const int* row_index  = (const int*)d_in[17];
  const int* src_index  = (const int*)d_in[18];
  const int* org_to_src = (const int*)d_in[19];

  char* ws = (char*)d_ws;
  u16*   zatt = (u16*)(ws + OFF_ZATT);
  u16*   zcat = (u16*)(ws + OFF_ZCAT);
  u16*   wqk  = (u16*)(ws + OFF_WQK);
  float* bqk  = (float*)(ws + OFF_BQK);
  u16*   win  = (u16*)(ws + OFF_WIN);
  u16*   wout = (u16*)(ws + OFF_WOUT);
  unsigned char* qk8 = (unsigned char*)(ws + OFF_QK);
  int*   bkt  = (int*)(ws + OFF_BKT);
  u16*   hbf  = (u16*)(ws + OFF_HBF);
  float* rec  = (float*)(ws + OFF_REC);
  int*   cntp = (int*)(ws + OFF_CNTP);

  static bool s_attr = false;
  if (!s_attr) {
    hipFuncSetAttribute(reinterpret_cast<const void*>(&gemm256<4, 3>),
                        hipFuncAttributeMaxDynamicSharedMemorySize, 131072);
    hipFuncSetAttribute(reinterpret_cast<const void*>(&gemm256<1, 3>),
                        hipFuncAttributeMaxDynamicSharedMemorySize, 131072);
    s_attr = true;
  }

  hipMemsetAsync(ws + OFF_CNTP, 0, 16384 * 64, stream);

  prep_edges<<<E_EDGES / 256, 256, 0, stream>>>(
      row_index, att_bias, dist, src_pos, src_index, org_to_src, cntp, bkt, rec);
  prep_wln<3><<<2304 + N_NODES / 4, 256, 0, stream>>>(
      Wq, Wk, bq, bk, W_in, W_out, wqk, bqk, win, wout,
      x, g_att, b_att, g_mlp, b_mlp, zatt, zcat);
  gemm256<4, 3><<<dim3(64, 4), 512, 131072, stream>>>(zatt, wqk, bqk, qk8, N_NODES, 1024, 512);
  edge_csr<<<N_NODES / 4, 256, 0, stream>>>(qk8, rec, cntp, bkt, pos, zcat);
  gemm256<1, 3><<<dim3(64, 4), 512, 131072, stream>>>(zcat, win, b_in, hbf, N_NODES, 1024, KIN);
  gemm_nt<2, 2, 3><<<dim3(128, 4), 256, 0, stream>>>(hbf, wout, b_out, x, d_out, N_NODES, 512, 1024);
}

// Round 8
// 254.580 us; speedup vs baseline: 1.3274x; 1.3274x over previous
//
#include <hip/hip_runtime.h>
#include <math.h>

// PositionFeaturizer on MI355X — round 15:
//  * Diagnostic r14 findings: gemm_nt (gemm3) ~21 us true, running at the
//    m97-structure ~900 TF ceiling even L3-warm; gemm256s + prep_wln bodies
//    sum to only ~40-60 us. GEMMs were never the assumed 120-us pool.
//  * NEW gemm_mlp: gemm3 ported to the deep-pipelined schedule at
//    BM=256 x BN=128 (grid 64x4 = 256 blocks = 1/CU; 256^2 would idle half
//    the GPU at N=512). 2 phases/K-tile, 3 staged loads/phase, counted
//    vmcnt(6) (queue: prologue 9 loads, drain 3/phase, 2-phase landing
//    slack), slot-offset staging (no phase writes a slot it reads),
//    granule-XOR swizzle both-sides. Predict 21 -> ~13 us.
//  * prep_edges + prep_wln re-merged into prep_all (one dispatch, r11-style
//    block partition: [0,1024) edges, [1024,3328) weights, rest LN).
//  * REP diagnostic removed; structure otherwise = r12 (best, 256.5).

typedef unsigned short u16;
typedef __attribute__((ext_vector_type(8))) short bf16x8;   // 8 bf16 in 4 VGPRs
typedef __attribute__((ext_vector_type(4))) float f32x4;
typedef __attribute__((ext_vector_type(2))) float f32x2;

constexpr int N_NODES = 16384;
constexpr int E_EDGES = 262144;
constexpr int D = 512;
constexpr int KIN = 576;    // 536 padded to 9*64

// workspace layout (bytes)
constexpr size_t OFF_ZATT = 0;                       // 16384*512*2  = 16,777,216
constexpr size_t OFF_ZCAT = 16777216;                // 16384*576*2  = 18,874,368
constexpr size_t OFF_WQK  = 35651584;                // 1024*512*2   = 1,048,576
constexpr size_t OFF_BQK  = 36700160;                // 1024*4       = 4,096
constexpr size_t OFF_WIN  = 36704256;                // 1024*576*2   = 1,179,648
constexpr size_t OFF_WOUT = 37883904;                // 512*1024*2   = 1,048,576
constexpr size_t OFF_QK   = 38932480;                // 16384*1024*1 = 16,777,216 (fp8)
constexpr size_t OFF_BKT  = 55775232;                // 16384*64*4 = 4,194,304
constexpr size_t OFF_HBF  = 59969536;                // 16384*1024*2 = 33,554,432
constexpr size_t OFF_REC  = 93523968;                // 262144*64 = 16,777,216
constexpr size_t OFF_CNTP = 110301184;               // 16384*64 = 1,048,576

static __device__ __forceinline__ u16 f2bf(float f) {
  union { float f; unsigned int u; } v; v.f = f;
  unsigned int u = v.u;
  u = u + 0x7FFFu + ((u >> 16) & 1u);   // RNE
  return (u16)(u >> 16);
}
// async global->LDS, 16 B per lane; LDS dest = wave-uniform base + lane*16
static __device__ __forceinline__ void gload16(const u16* g, u16* l) {
  __builtin_amdgcn_global_load_lds(
      (const __attribute__((address_space(1))) unsigned int*)g,
      (__attribute__((address_space(3))) unsigned int*)l, 16, 0, 0);
}

// ---------------------------------------------------------------- fused prep: edges + weights + dual LN
__global__ __launch_bounds__(256) void prep_all(
    const int* __restrict__ row_index,
    const float* __restrict__ att_bias, const float* __restrict__ dist,
    const float* __restrict__ src_pos, const int* __restrict__ src_index,
    const int* __restrict__ org_to_src,
    int* __restrict__ cntp, int* __restrict__ bucket, float* __restrict__ rec,
    const float* __restrict__ Wq, const float* __restrict__ Wk,
    const float* __restrict__ bq, const float* __restrict__ bk,
    const float* __restrict__ W_in, const float* __restrict__ W_out,
    u16* __restrict__ wqk, float* __restrict__ bqk,
    u16* __restrict__ win, u16* __restrict__ wout,
    const float* __restrict__ x,
    const float* __restrict__ g1, const float* __restrict__ b1,
    const float* __restrict__ g2, const float* __restrict__ b2,
    u16* __restrict__ zatt, u16* __restrict__ zcat)
{
  if (blockIdx.x < 1024) {
    // ------- edge records + bucket CSR (1024 blocks) -------
    const int gid = blockIdx.x * 256 + threadIdx.x;   // < E_EDGES
    const int r = row_index[gid];
    const int s = src_index[gid];
    const float dv = dist[gid];
    float4 q0, q1, q2, q3;
    q0.x = att_bias[gid];
    q0.y = att_bias[(size_t)1 * E_EDGES + gid];
    q0.z = att_bias[(size_t)2 * E_EDGES + gid];
    q0.w = att_bias[(size_t)3 * E_EDGES + gid];
    q1.x = att_bias[(size_t)4 * E_EDGES + gid];
    q1.y = att_bias[(size_t)5 * E_EDGES + gid];
    q1.z = att_bias[(size_t)6 * E_EDGES + gid];
    q1.w = att_bias[(size_t)7 * E_EDGES + gid];
    q2.x = (dv == 0.f) ? 0.f : 1.f / dv;   // matches ref: inv = 1/dist, then mul
    q2.y = src_pos[(size_t)s * 3 + 0];
    q2.z = src_pos[(size_t)s * 3 + 1];
    q2.w = src_pos[(size_t)s * 3 + 2];
    q3.x = __int_as_float(org_to_src[s]);
    q3.y = 0.f; q3.z = 0.f; q3.w = 0.f;
    float4* rg = (float4*)(rec + (size_t)gid * 16);
    rg[0] = q0; rg[1] = q1; rg[2] = q2; rg[3] = q3;
    const int p = atomicAdd(&cntp[r * 16], 1);   // 1 counter per 64-B line
    if (p < 64) bucket[(size_t)r * 64 + p] = gid;
    return;
  }
  if (blockIdx.x < 3328) {
    // ------- weight casts (2304 blocks) -------
    const int gid = (blockIdx.x - 1024) * 256 + threadIdx.x;
    if (gid < 512 * 1024) {
      wqk[gid]  = f2bf(gid < 512 * 512 ? Wq[gid] : Wk[gid - 512 * 512]);
      wout[gid] = f2bf(W_out[gid]);
    }
    if (gid < 1024 * KIN) {
      const int r = gid / KIN, c = gid - r * KIN;
      win[gid] = f2bf(c < 536 ? W_in[r * 536 + c] : 0.f);
    }
    if (gid < 1024) bqk[gid] = gid < 512 ? bq[gid] : bk[gid - 512];
    return;
  }
  // ------- dual layernorm, wave-per-row (4096 blocks x 4 rows) -------
  const int row = (blockIdx.x - 3328) * 4 + (threadIdx.x >> 6);
  const int l = threadIdx.x & 63;
  const float* xr = x + (size_t)row * D + l * 8;
  const float4 v0 = *(const float4*)(xr);
  const float4 v1 = *(const float4*)(xr + 4);
  float s  = v0.x + v0.y + v0.z + v0.w + v1.x + v1.y + v1.z + v1.w;
  float s2 = v0.x * v0.x + v0.y * v0.y + v0.z * v0.z + v0.w * v0.w
           + v1.x * v1.x + v1.y * v1.y + v1.z * v1.z + v1.w * v1.w;
#pragma unroll
  for (int m = 1; m < 64; m <<= 1) {
    s  += __shfl_xor(s, m, 64);
    s2 += __shfl_xor(s2, m, 64);
  }
  const float mu = s * (1.f / D);
  const float var = s2 * (1.f / D) - mu * mu;
  const float rs = rsqrtf(var + 1e-5f);
  const int c0 = l * 8;
  const float4 ga0 = *(const float4*)(g1 + c0), ga1 = *(const float4*)(g1 + c0 + 4);
  const float4 ba0 = *(const float4*)(b1 + c0), ba1 = *(const float4*)(b1 + c0 + 4);
  const float4 gm0 = *(const float4*)(g2 + c0), gm1 = *(const float4*)(g2 + c0 + 4);
  const float4 bm0 = *(const float4*)(b2 + c0), bm1 = *(const float4*)(b2 + c0 + 4);
  float n[8] = { (v0.x - mu) * rs, (v0.y - mu) * rs, (v0.z - mu) * rs, (v0.w - mu) * rs,
                 (v1.x - mu) * rs, (v1.y - mu) * rs, (v1.z - mu) * rs, (v1.w - mu) * rs };
  const float ga[8] = { ga0.x, ga0.y, ga0.z, ga0.w, ga1.x, ga1.y, ga1.z, ga1.w };
  const float ba[8] = { ba0.x, ba0.y, ba0.z, ba0.w, ba1.x, ba1.y, ba1.z, ba1.w };
  const float gm[8] = { gm0.x, gm0.y, gm0.z, gm0.w, gm1.x, gm1.y, gm1.z, gm1.w };
  const float bm[8] = { bm0.x, bm0.y, bm0.z, bm0.w, bm1.x, bm1.y, bm1.z, bm1.w };
  bf16x8 za, zc;
#pragma unroll
  for (int i = 0; i < 8; ++i) {
    za[i] = (short)f2bf(n[i] * ga[i] + ba[i]);
    zc[i] = (short)f2bf(n[i] * gm[i] + bm[i]);
  }
  *(bf16x8*)(zatt + (size_t)row * D + c0) = za;
  *(bf16x8*)(zcat + (size_t)row * KIN + c0) = zc;
  if (l < 32) ((unsigned int*)(zcat + (size_t)row * KIN + D))[l] = 0;  // feat+pad zero
}

// ---------------------------------------------------------------- 256^2 8-wave deep-pipelined NT GEMM
#define MM_BLK(AF, BF, NB) do {                                               \
  __builtin_amdgcn_s_setprio(1);                                              \
  _Pragma("unroll")                                                           \
  for (int mi = 0; mi < 8; ++mi) {                                            \
    acc[mi][NB]     = __builtin_amdgcn_mfma_f32_16x16x32_bf16(AF[mi], BF[0], acc[mi][NB], 0, 0, 0);     \
    acc[mi][NB + 1] = __builtin_amdgcn_mfma_f32_16x16x32_bf16(AF[mi], BF[1], acc[mi][NB + 1], 0, 0, 0); \
  }                                                                           \
  __builtin_amdgcn_s_setprio(0);                                              \
} while (0)

template <int EPI>
__global__ __launch_bounds__(512, 2) void gemm256(
    const u16* __restrict__ A, const u16* __restrict__ B,
    const float* __restrict__ bias,
    void* __restrict__ Cout, int M, int Nn, int K)
{
  extern __shared__ __align__(16) u16 lds[];   // 65536 u16 = 128 KiB
  const int tid = threadIdx.x;
  const int lane = tid & 63;
  const int wave = tid >> 6;          // 0..7
  const int wave_m = wave >> 2;
  const int wave_n = wave & 3;
  const int m0 = blockIdx.x * 256;
  const int n0 = blockIdx.y * 256;
  const int fr = lane & 15;
  const int fq = lane >> 4;
  const int NT = K >> 6;
  const int sw = (fq ^ ((fr >> 1) & 3)) * 8;

  f32x4 acc[8][4];
#pragma unroll
  for (int i = 0; i < 8; ++i)
#pragma unroll
    for (int j = 0; j < 4; ++j) acc[i][j] = 0.f;

  auto stageA = [&](int slot, int ktile, int kh) {
    u16* base = lds + slot * 8192;
    const int kb = ktile * 64 + kh * 32;
#pragma unroll
    for (int r = 0; r < 2; ++r) {
      const int g = r * 512 + tid;
      const int row = g >> 2;
      const int gs = (g & 3) ^ ((row >> 1) & 3);
      gload16(A + (size_t)(m0 + row) * K + kb + gs * 8,
              base + (r * 512 + wave * 64) * 8);
    }
  };
  auto stageB = [&](int slot, int ktile, int kh) {
    u16* base = lds + 32768 + slot * 8192;
    const int kb = ktile * 64 + kh * 32;
#pragma unroll
    for (int r = 0; r < 2; ++r) {
      const int g = r * 512 + tid;
      const int row = g >> 2;
      const int gs = (g & 3) ^ ((row >> 1) & 3);
      gload16(B + (size_t)(n0 + row) * K + kb + gs * 8,
              base + (r * 512 + wave * 64) * 8);
    }
  };
  auto ldA = [&](bf16x8 (&af)[8], int slot) {
    const u16* p = lds + slot * 8192 + (wave_m * 128 + fr) * 32 + sw;
#pragma unroll
    for (int mi = 0; mi < 8; ++mi)
      af[mi] = *(const bf16x8*)(p + mi * 16 * 32);
  };
  auto ldB = [&](bf16x8 (&bf)[2], int slot, int nh) {
    const u16* p = lds + 32768 + slot * 8192 + (wave_n * 64 + nh * 32 + fr) * 32 + sw;
    bf[0] = *(const bf16x8*)(p);
    bf[1] = *(const bf16x8*)(p + 16 * 32);
  };

  stageA(0, 0, 0); stageB(0, 0, 0);
  stageA(1, 0, 1); stageB(1, 0, 1);
  stageA(2, 1, 0); stageB(2, 1, 0);
  stageA(3, 1, 1);
  asm volatile("s_waitcnt vmcnt(10)" ::: "memory");
  __builtin_amdgcn_s_barrier();
  asm volatile("" ::: "memory");

  bf16x8 af[8], bf0[2], bf1[2];
  for (int t = 0; t < NT; ++t) {
    const int sa0 = (2 * t) & 3,  sa1 = (2 * t + 1) & 3;
    const int sb1n = (2 * t + 3) & 3;
    const int t1 = (t + 1 >= NT) ? t + 1 - NT : t + 1;
    const int t2 = (t + 2 >= NT) ? t + 2 - NT : t + 2;

    ldA(af, sa0); ldB(bf0, sa0, 0);
    stageB(sb1n, t1, 1);
    __builtin_amdgcn_s_barrier();
    asm volatile("" ::: "memory");
    MM_BLK(af, bf0, 0);
    __builtin_amdgcn_s_barrier();
    asm volatile("" ::: "memory");
    ldB(bf1, sa0, 1);
    stageA(sa0, t2, 0);
    __builtin_amdgcn_s_barrier();
    asm volatile("" ::: "memory");
    MM_BLK(af, bf1, 2);
    asm volatile("s_waitcnt vmcnt(10)" ::: "memory");
    __builtin_amdgcn_s_barrier();
    asm volatile("" ::: "memory");
    ldA(af, sa1); ldB(bf0, sa1, 0);
    stageB(sa0, t2, 0);
    __builtin_amdgcn_s_barrier();
    asm volatile("" ::: "memory");
    MM_BLK(af, bf0, 0);
    __builtin_amdgcn_s_barrier();
    asm volatile("" ::: "memory");
    ldB(bf1, sa1, 1);
    stageA(sa1, t2, 1);
    __builtin_amdgcn_s_barrier();
    asm volatile("" ::: "memory");
    MM_BLK(af, bf1, 2);
    asm volatile("s_waitcnt vmcnt(10)" ::: "memory");
    __builtin_amdgcn_s_barrier();
    asm volatile("" ::: "memory");
  }
  asm volatile("s_waitcnt vmcnt(0)" ::: "memory");

#pragma unroll
  for (int mi = 0; mi < 8; ++mi) {
#pragma unroll
    for (int nj = 0; nj < 4; ++nj) {
      const int col = n0 + wave_n * 64 + nj * 16 + fr;
      const float bv = bias[col];
#pragma unroll
      for (int rr = 0; rr < 4; ++rr) {
        const int row = m0 + wave_m * 128 + mi * 16 + fq * 4 + rr;
        float v = acc[mi][nj][rr] + bv;
        if (EPI == 1) {
          const float nu = -1.5957691216057308f * (v + 0.044715f * v * v * v);
          const float sg = __builtin_amdgcn_rcpf(1.f + __expf(nu));
          ((u16*)Cout)[(size_t)row * Nn + col] = f2bf(v * sg);
        } else {
          const int pk = __builtin_amdgcn_cvt_pk_fp8_f32(v, v, 0, false);
          ((unsigned char*)Cout)[(size_t)row * Nn + col] = (unsigned char)(pk & 0xFF);
        }
      }
    }
  }
}

// ---------------------------------------------------------------- gemm3: deep-pipelined BM=256 x BN=128 (grid 64x4 = 1/CU)
// C[M,512] = A[M,1024] @ B[512,1024]^T + bias + resid (f32 out).
// 8 waves (2M x 4N): per-wave 128x32 out = acc[8][2]. 2 phases/K-tile:
//   Pk0(t): read slots (t,k0); stage (t+1,k1); bar; 16 MFMA; vmcnt(6) bar
//   Pk1(t): read slots (t,k1); stage (t+2,k0); bar; 16 MFMA; vmcnt(6) bar
// Queue: prologue 9 loads, 3 staged/phase, drain 3/phase -> vmcnt(6) gives
// each stage a 2-phase landing window. No phase writes a slot it reads
// (Pk0 reads sa0, writes (2t+3)&3; Pk1 reads sa1, writes sa0 after barrier).
__global__ __launch_bounds__(512, 2) void gemm_mlp(
    const u16* __restrict__ A, const u16* __restrict__ B,
    const float* __restrict__ bias, const float* __restrict__ resid,
    float* __restrict__ Cout, int M, int Nn, int K)
{
  extern __shared__ __align__(16) u16 lds[];   // A: 4 x 8192 u16; B: 4 x 4096 u16 at +32768
  const int tid = threadIdx.x;
  const int lane = tid & 63;
  const int wave = tid >> 6;
  const int wave_m = wave >> 2;       // 0..1
  const int wave_n = wave & 3;        // 0..3
  const int m0 = blockIdx.x * 256;
  const int n0 = blockIdx.y * 128;
  const int fr = lane & 15;
  const int fq = lane >> 4;
  const int NT = K >> 6;              // 16
  const int sw = (fq ^ ((fr >> 1) & 3)) * 8;

  f32x4 acc[8][2];
#pragma unroll
  for (int i = 0; i < 8; ++i) { acc[i][0] = 0.f; acc[i][1] = 0.f; }

  auto stageA = [&](int slot, int ktile, int kh) {     // [256][32], 2 gloads
    u16* base = lds + slot * 8192;
    const int kb = ktile * 64 + kh * 32;
#pragma unroll
    for (int r = 0; r < 2; ++r) {
      const int g = r * 512 + tid;
      const int row = g >> 2;
      const int gs = (g & 3) ^ ((row >> 1) & 3);
      gload16(A + (size_t)(m0 + row) * K + kb + gs * 8,
              base + (r * 512 + wave * 64) * 8);
    }
  };
  auto stageB = [&](int slot, int ktile, int kh) {     // [128][32], 1 gload
    u16* base = lds + 32768 + slot * 4096;
    const int kb = ktile * 64 + kh * 32;
    const int row = tid >> 2;
    const int gs = (tid & 3) ^ ((row >> 1) & 3);
    gload16(B + (size_t)(n0 + row) * K + kb + gs * 8,
            base + (wave * 64 + lane) * 8);
  };
  auto ldA = [&](bf16x8 (&af)[8], int slot) {
    const u16* p = lds + slot * 8192 + (wave_m * 128 + fr) * 32 + sw;
#pragma unroll
    for (int mi = 0; mi < 8; ++mi)
      af[mi] = *(const bf16x8*)(p + mi * 16 * 32);
  };
  auto ldB2 = [&](bf16x8 (&bf)[2], int slot) {
    const u16* p = lds + 32768 + slot * 4096 + (wave_n * 32 + fr) * 32 + sw;
    bf[0] = *(const bf16x8*)(p);
    bf[1] = *(const bf16x8*)(p + 16 * 32);
  };

  // prologue: (0,k0) (0,k1) (1,k0) = 9 loads; drain first 3
  stageA(0, 0, 0); stageB(0, 0, 0);
  stageA(1, 0, 1); stageB(1, 0, 1);
  stageA(2, 1, 0); stageB(2, 1, 0);
  asm volatile("s_waitcnt vmcnt(6)" ::: "memory");
  __builtin_amdgcn_s_barrier();
  asm volatile("" ::: "memory");

  bf16x8 af[8], bf[2];
  for (int t = 0; t < NT; ++t) {
    const int sa0 = (2 * t) & 3, sa1 = (2 * t + 1) & 3;
    const int sn  = (2 * t + 3) & 3;                   // slot of (t+1,k1)
    const int t1 = (t + 1 >= NT) ? t + 1 - NT : t + 1; // wrap: never read
    const int t2 = (t + 2 >= NT) ? t + 2 - NT : t + 2;

    // Pk0
    ldA(af, sa0); ldB2(bf, sa0);
    stageA(sn, t1, 1); stageB(sn, t1, 1);
    __builtin_amdgcn_s_barrier();
    asm volatile("" ::: "memory");
    MM_BLK(af, bf, 0);
    asm volatile("s_waitcnt vmcnt(6)" ::: "memory");   // (t,k1) landed
    __builtin_amdgcn_s_barrier();
    asm volatile("" ::: "memory");
    // Pk1
    ldA(af, sa1); ldB2(bf, sa1);
    stageA(sa0, t2, 0); stageB(sa0, t2, 0);
    __builtin_amdgcn_s_barrier();
    asm volatile("" ::: "memory");
    MM_BLK(af, bf, 0);
    asm volatile("s_waitcnt vmcnt(6)" ::: "memory");   // (t+1,k0) landed
    __builtin_amdgcn_s_barrier();
    asm volatile("" ::: "memory");
  }
  asm volatile("s_waitcnt vmcnt(0)" ::: "memory");     // drain wrapped garbage

  // epilogue: + bias + x residual, f32 out
#pragma unroll
  for (int mi = 0; mi < 8; ++mi) {
#pragma unroll
    for (int nj = 0; nj < 2; ++nj) {
      const int col = n0 + wave_n * 32 + nj * 16 + fr;
      const float bv = bias[col];
#pragma unroll
      for (int rr = 0; rr < 4; ++rr) {
        const int row = m0 + wave_m * 128 + mi * 16 + fq * 4 + rr;
        Cout[(size_t)row * Nn + col] = acc[mi][nj][rr] + bv + resid[(size_t)row * Nn + col];
      }
    }
  }
}

// ---------------------------------------------------------------- edge pass (bucket CSR + edge records)
// 4-stage pipeline: bucket@i+4, rec@i+3, kv@i+2, compute@i.
__global__ __launch_bounds__(256) void edge_csr(
    const unsigned char* __restrict__ qk8, const float* __restrict__ rec,
    const int* __restrict__ cntp, const int* __restrict__ bucket,
    const float* __restrict__ pos, u16* __restrict__ zcat)
{
  const int lane = threadIdx.x & 63;
  const int wave = threadIdx.x >> 6;
  const int row = blockIdx.x * 4 + wave;
  const int half = lane >> 5;
  const int sub = lane & 31;
  const int h = sub >> 2, j = sub & 3;
  const int deg = min(cntp[row * 16], 64);
  const int base = row * 64;

  const uint4 qv = *(const uint4*)(qk8 + (size_t)row * 1024 + sub * 16);
  float qf[16];
  {
    const unsigned int* qu = (const unsigned int*)&qv;
#pragma unroll
    for (int i = 0; i < 4; ++i) {
      const f32x2 lo = __builtin_amdgcn_cvt_pk_f32_fp8(qu[i], false);
      const f32x2 hi = __builtin_amdgcn_cvt_pk_f32_fp8(qu[i], true);
      qf[i * 4 + 0] = lo.x; qf[i * 4 + 1] = lo.y;
      qf[i * 4 + 2] = hi.x; qf[i * 4 + 3] = hi.y;
    }
  }

  float accA = 0.f, accB = 0.f;
  const int npair = (deg + 1) >> 1;

  bool ok0 = half < deg;
  int e0 = ok0 ? bucket[base + half] : 0;
  const float* r0 = rec + (size_t)e0 * 16;
  float bias0 = r0[h], invd0 = r0[8];
  float spA0 = (j >= 2) ? r0[7 + j] : 0.f;
  float spB0 = (j == 1) ? r0[11] : 0.f;
  uint4 kv0 = *(const uint4*)(qk8 + (size_t)__float_as_int(r0[12]) * 1024 + 512 + sub * 16);

  bool ok1 = 2 + half < deg;
  int e1 = ok1 ? bucket[base + 2 + half] : 0;
  const float* r1 = rec + (size_t)e1 * 16;
  float bias1 = r1[h], invd1 = r1[8];
  float spA1 = (j >= 2) ? r1[7 + j] : 0.f;
  float spB1 = (j == 1) ? r1[11] : 0.f;
  uint4 kv1 = *(const uint4*)(qk8 + (size_t)__float_as_int(r1[12]) * 1024 + 512 + sub * 16);

  bool ok2 = 4 + half < deg;
  int e2 = ok2 ? bucket[base + 4 + half] : 0;
  const float* r2p = rec + (size_t)e2 * 16;
  float bias2 = r2p[h], invd2 = r2p[8];
  float spA2 = (j >= 2) ? r2p[7 + j] : 0.f;
  float spB2 = (j == 1) ? r2p[11] : 0.f;
  int kr2 = __float_as_int(r2p[12]);

  bool ok3 = 6 + half < deg;
  int e3 = ok3 ? bucket[base + 6 + half] : 0;

  for (int i = 0; i < npair; ++i) {
    const uint4 kv2 = *(const uint4*)(qk8 + (size_t)kr2 * 1024 + 512 + sub * 16);
    const float* r3 = rec + (size_t)e3 * 16;
    const float bias3 = r3[h], invd3 = r3[8];
    const float spA3 = (j >= 2) ? r3[7 + j] : 0.f;
    const float spB3 = (j == 1) ? r3[11] : 0.f;
    const int kr3 = __float_as_int(r3[12]);
    const bool ok4 = 2 * (i + 4) + half < deg;
    const int e4 = ok4 ? bucket[base + 2 * (i + 4) + half] : 0;

    float p;
    {
      const unsigned int* ku = (const unsigned int*)&kv0;
      const f32x2 a0 = __builtin_amdgcn_cvt_pk_f32_fp8(ku[0], false);
      const f32x2 a1 = __builtin_amdgcn_cvt_pk_f32_fp8(ku[0], true);
      const f32x2 b0 = __builtin_amdgcn_cvt_pk_f32_fp8(ku[1], false);
      const f32x2 b1 = __builtin_amdgcn_cvt_pk_f32_fp8(ku[1], true);
      const f32x2 c0 = __builtin_amdgcn_cvt_pk_f32_fp8(ku[2], false);
      const f32x2 c1 = __builtin_amdgcn_cvt_pk_f32_fp8(ku[2], true);
      const f32x2 d0 = __builtin_amdgcn_cvt_pk_f32_fp8(ku[3], false);
      const f32x2 d1 = __builtin_amdgcn_cvt_pk_f32_fp8(ku[3], true);
      p = qf[0] * a0.x;
      p = fmaf(qf[1],  a0.y, p);  p = fmaf(qf[2],  a1.x, p);  p = fmaf(qf[3],  a1.y, p);
      p = fmaf(qf[4],  b0.x, p);  p = fmaf(qf[5],  b0.y, p);  p = fmaf(qf[6],  b1.x, p);
      p = fmaf(qf[7],  b1.y, p);  p = fmaf(qf[8],  c0.x, p);  p = fmaf(qf[9],  c0.y, p);
      p = fmaf(qf[10], c1.x, p);  p = fmaf(qf[11], c1.y, p);  p = fmaf(qf[12], d0.x, p);
      p = fmaf(qf[13], d0.y, p);  p = fmaf(qf[14], d1.x, p);  p = fmaf(qf[15], d1.y, p);
    }
    p += __shfl_xor(p, 1, 64);
    p += __shfl_xor(p, 2, 64);
    float pe = __expf(p * 0.125f + bias0);
    pe = ok0 ? pe : 0.f;
    const float w = pe * invd0;
    accA += (j == 0) ? pe : (j == 1) ? w : w * spA0;
    accB += w * spB0;

    ok0 = ok1; bias0 = bias1; invd0 = invd1; spA0 = spA1; spB0 = spB1; kv0 = kv1;
    ok1 = ok2; bias1 = bias2; invd1 = invd2; spA1 = spA2; spB1 = spB2; kv1 = kv2;
    ok2 = ok3; bias2 = bias3; invd2 = invd3; spA2 = spA3; spB2 = spB3; kr2 = kr3;
    ok3 = ok4; e3 = e4;
  }

  accA += __shfl_xor(accA, 32, 64);
  accB += __shfl_xor(accB, 32, 64);
  const int hb = h << 2;
  const float den  = __shfl(accA, hb + 0, 64);
  const float wsum = __shfl(accA, hb + 1, 64);
  const float wsp01 = __shfl(accA, hb + 2 + (j & 1), 64);
  const float wsp2  = __shfl(accB, hb + 1, 64);
  const float invd = (den != 0.f) ? 1.f / den : 0.f;
  const float rsum = wsum * invd;
  if (half == 0 && j < 3) {
    const float wspj = (j < 2) ? wsp01 : wsp2;
    zcat[(size_t)row * KIN + D + h * 3 + j] = f2bf(wspj * invd - rsum * pos[row * 3 + j]);
  }
}

// ---------------------------------------------------------------- launch
extern "C" void kernel_launch(void* const* d_in, const int* in_sizes, int n_in,
                              void* d_out, int out_size, void* d_ws, size_t ws_size,
                              hipStream_t stream)
{
  const float* x        = (const float*)d_in[0];
  const float* Wq       = (const float*)d_in[1];
  const float* bq       = (const float*)d_in[2];
  const float* Wk       = (const float*)d_in[3];
  const float* bk       = (const float*)d_in[4];
  const float* g_att    = (const float*)d_in[5];
  const float* b_att    = (const float*)d_in[6];
  const float* g_mlp    = (const float*)d_in[7];
  const float* b_mlp    = (const float*)d_in[8];
  const float* W_in     = (const float*)d_in[9];
  const float* b_in     = (const float*)d_in[10];
  const float* W_out    = (const float*)d_in[11];
  const float* b_out    = (const float*)d_in[12];
  const float* att_bias = (const float*)d_in[13];
  const float* dist     = (const float*)d_in[14];
  const float* pos      = (const float*)d_in[15];
  const float* src_pos  = (const float*)d_in[16];
  const int* row_index  = (const int*)d_in[17];
  const int* src_index  = (const int*)d_in[18];
  const int* org_to_src = (const int*)d_in[19];

  char* ws = (char*)d_ws;
  u16*   zatt = (u16*)(ws + OFF_ZATT);
  u16*   zcat = (u16*)(ws + OFF_ZCAT);
  u16*   wqk  = (u16*)(ws + OFF_WQK);
  float* bqk  = (float*)(ws + OFF_BQK);
  u16*   win  = (u16*)(ws + OFF_WIN);
  u16*   wout = (u16*)(ws + OFF_WOUT);
  unsigned char* qk8 = (unsigned char*)(ws + OFF_QK);
  int*   bkt  = (int*)(ws + OFF_BKT);
  u16*   hbf  = (u16*)(ws + OFF_HBF);
  float* rec  = (float*)(ws + OFF_REC);
  int*   cntp = (int*)(ws + OFF_CNTP);

  static bool s_attr = false;
  if (!s_attr) {
    hipFuncSetAttribute(reinterpret_cast<const void*>(&gemm256<4>),
                        hipFuncAttributeMaxDynamicSharedMemorySize, 131072);
    hipFuncSetAttribute(reinterpret_cast<const void*>(&gemm256<1>),
                        hipFuncAttributeMaxDynamicSharedMemorySize, 131072);
    hipFuncSetAttribute(reinterpret_cast<const void*>(&gemm_mlp),
                        hipFuncAttributeMaxDynamicSharedMemorySize, 98304);
    s_attr = true;
  }

  hipMemsetAsync(ws + OFF_CNTP, 0, 16384 * 64, stream);

  prep_all<<<1024 + 2304 + N_NODES / 4, 256, 0, stream>>>(
      row_index, att_bias, dist, src_pos, src_index, org_to_src, cntp, bkt, rec,
      Wq, Wk, bq, bk, W_in, W_out, wqk, bqk, win, wout,
      x, g_att, b_att, g_mlp, b_mlp, zatt, zcat);
  gemm256<4><<<dim3(64, 4), 512, 131072, stream>>>(zatt, wqk, bqk, qk8, N_NODES, 1024, 512);
  edge_csr<<<N_NODES / 4, 256, 0, stream>>>(qk8, rec, cntp, bkt, pos, zcat);
  gemm256<1><<<dim3(64, 4), 512, 131072, stream>>>(zcat, win, b_in, hbf, N_NODES, 1024, KIN);
  gemm_mlp<<<dim3(64, 4), 512, 98304, stream>>>(hbf, wout, b_out, x, (float*)d_out, N_NODES, 512, 1024);
}